// Round 8
// baseline (341.938 us; speedup 1.0000x reference)
//
#include <hip/hip_runtime.h>

// Problem constants (from reference)
#define NUM_NODES 100000
#define MAX_DEGREE 128
#define NODE_DIM 256
#define VERT_NUM 16384
#define NUM_SAMPLES 32
#define SENTINEL (NUM_NODES - 1)

#define TVPB 8                    // vertices per tile
#define TILES 2                   // tiles per block (MUST stay 2: at T>=3 the
                                  // adj/A stage of tile s+1 would race ein's
                                  // read of tile s-1 in the same buffer)
#define VPBLK (TVPB * TILES)      // 16 vertices per block
#define NBLK (VERT_NUM / VPBLK)   // 1024 blocks
#define NTHR 512                  // waves 0-3: matmul (mm), waves 4-7: einsum (ein)

// Output layout (FLOAT32 elements), concatenated in reference return order:
// adj_out [V*S] | att_lists [V*S] | adj_lists_numnz [V] | out_mean [V]
#define ADJ_OFF 0
#define ATT_OFF (VERT_NUM * NUM_SAMPLES)
#define NNZ_OFF (2 * VERT_NUM * NUM_SAMPLES)
#define MEAN_OFF (2 * VERT_NUM * NUM_SAMPLES + VERT_NUM)

__device__ __forceinline__ float bfbits2f(unsigned int bits16) {
    return __uint_as_float(bits16 << 16);
}

// Probe: is float storage f32 (1) or packed bf16 (0)?
__device__ __forceinline__ int probe_isf32(const void* p) {
    const unsigned int* fu = (const unsigned int*)p;
    int cnt = 0;
    for (int i = 0; i < 64; ++i) {
        const unsigned int w = fu[i];
        const unsigned int e2 = (w >> 7) & 0xFFu;
        if (e2 >= 90u && e2 <= 140u && (w & 0xFFFFu) != 0u) ++cnt;
    }
    return (cnt >= 40) ? 0 : 1;
}

// Templated loads: no per-element select, vectorized when f32.
template <int ISF32>
__device__ __forceinline__ float ld1(const void* p, size_t idx) {
    if (ISF32) return ((const float*)p)[idx];
    return bfbits2f(((const unsigned short*)p)[idx]);
}

template <int ISF32>
__device__ __forceinline__ float4 load4(const void* p, size_t idx) {
    if (ISF32) {
        return *(const float4*)((const float*)p + idx);
    } else {
        const ushort4 u = *(const ushort4*)((const unsigned short*)p + idx);
        float4 v;
        v.x = bfbits2f(u.x); v.y = bfbits2f(u.y);
        v.z = bfbits2f(u.z); v.w = bfbits2f(u.w);
        return v;
    }
}

// ---------------------------------------------------------------------------
// R8: wave-specialized pipeline. Waves 0-3 (mm) run the R4-proven matmul
// (1 col x 8 verts, fp64 acc, W-quad prefetch, k-ascending order). Waves 4-7
// (ein) run the R4-proven einsum (2-deep pipeline, identical FMA + butterfly
// order). Block processes TILES=2 tiles through 3 slots:
//   s0: mm(t0)+stage(t1) | s1: mm(t1) || ein(t0) | s2: ein(t1)
// so chip-wide the VALU-heavy matmul and memory-heavy einsum overlap.
// A and L live in SEPARATE double-buffers (no overlay) -> no intra-slot
// barrier. s_out is gone: after the xor-butterfly ALL lanes hold the
// bit-identical sum; lane ln keeps sample so+ln in a register. Epilogue
// reproduces R4's exact reduction order via shfl_xor(16) pairing.
// ---------------------------------------------------------------------------
template <int ISF32>
__device__ __forceinline__ void body(
    const int* __restrict__ ids,
    const int* __restrict__ adj_info,
    const void* __restrict__ features,
    const void* __restrict__ W,
    const void* __restrict__ bias,
    float* __restrict__ out,
    float (*bufA)[TVPB][NODE_DIM + 4],
    float (*bufL)[TVPB][NODE_DIM + 4],
    int (*s_adj)[TVPB][NUM_SAMPLES],
    const int* s_ur,
    int tid, int v_blk)
{
    // ---- prologue: stage tile 0 (A rows + adj), all 512 threads ----
    {
        const int r = tid >> 6;          // 0..7 (wave-uniform)
        const int cg = (tid & 63) * 4;   // 0..252
        const float4 v = load4<ISF32>(features, (size_t)ids[v_blk + r] * NODE_DIM + cg);
        *(float4*)&bufA[0][r][cg] = v;
        if (tid < 256) {
            const int rr = tid >> 5;     // 0..7
            const int ss = tid & 31;
            s_adj[0][rr][ss] = adj_info[(size_t)ids[v_blk + rr] * MAX_DEGREE + s_ur[ss]];
        }
    }
    const int ur_mm = s_ur[tid & 31];    // for mm staging inside the loop
    __syncthreads();

    int cur = 0;
    for (int s = 0; s < TILES + 1; ++s) {
        if (tid < 256) {
            // =================== mm role ===================
            const int mmtile = s;
            if (mmtile < TILES) {
                // T14 split: issue next tile's stage loads before the matmul
                const bool do_stage = (mmtile + 1 < TILES);
                float4 st0, st1;
                int adjv = 0;
                if (do_stage) {
                    const int v0n = v_blk + (mmtile + 1) * TVPB;
                    const int i0 = tid;          // chunk 0..255
                    const int i1 = tid + 256;    // chunk 256..511
                    st0 = load4<ISF32>(features,
                        (size_t)ids[v0n + (i0 >> 6)] * NODE_DIM + (i0 & 63) * 4);
                    st1 = load4<ISF32>(features,
                        (size_t)ids[v0n + (i1 >> 6)] * NODE_DIM + (i1 & 63) * 4);
                    adjv = adj_info[(size_t)ids[v0n + (tid >> 5)] * MAX_DEGREE + ur_mm];
                }

                // ---- matmul tile mmtile: bufA[cur] -> bufL[cur] (R4 verbatim) ----
                {
                    const int col = tid;
                    double acc[TVPB];
                    #pragma unroll
                    for (int g = 0; g < TVPB; ++g) acc[g] = 0.0;
                    float wn0 = ld1<ISF32>(W, (size_t)0 * NODE_DIM + col);
                    float wn1 = ld1<ISF32>(W, (size_t)1 * NODE_DIM + col);
                    float wn2 = ld1<ISF32>(W, (size_t)2 * NODE_DIM + col);
                    float wn3 = ld1<ISF32>(W, (size_t)3 * NODE_DIM + col);
                    #pragma unroll 2
                    for (int k = 0; k < NODE_DIM; k += 4) {
                        const double w0 = (double)wn0;
                        const double w1 = (double)wn1;
                        const double w2 = (double)wn2;
                        const double w3 = (double)wn3;
                        if (k + 4 < NODE_DIM) {
                            wn0 = ld1<ISF32>(W, (size_t)(k + 4) * NODE_DIM + col);
                            wn1 = ld1<ISF32>(W, (size_t)(k + 5) * NODE_DIM + col);
                            wn2 = ld1<ISF32>(W, (size_t)(k + 6) * NODE_DIM + col);
                            wn3 = ld1<ISF32>(W, (size_t)(k + 7) * NODE_DIM + col);
                        }
                        #pragma unroll
                        for (int g = 0; g < TVPB; ++g) {
                            const float4 a = *(const float4*)&bufA[cur][g][k];
                            acc[g] = fma((double)a.x, w0, acc[g]);
                            acc[g] = fma((double)a.y, w1, acc[g]);
                            acc[g] = fma((double)a.z, w2, acc[g]);
                            acc[g] = fma((double)a.w, w3, acc[g]);
                        }
                    }
                    const double bv = (double)ld1<ISF32>(bias, (size_t)col);
                    #pragma unroll
                    for (int g = 0; g < TVPB; ++g)
                        bufL[cur][g][col] = (float)(acc[g] + bv);
                }

                if (do_stage) {   // write staged data (latency hidden by matmul)
                    const int nxt = cur ^ 1;
                    const int i0 = tid, i1 = tid + 256;
                    *(float4*)&bufA[nxt][i0 >> 6][(i0 & 63) * 4] = st0;
                    *(float4*)&bufA[nxt][i1 >> 6][(i1 & 63) * 4] = st1;
                    s_adj[nxt][tid >> 5][tid & 31] = adjv;
                }
            }
        } else {
            // =================== ein role ===================
            const int eintile = s - 1;
            if (eintile >= 0) {
                const int prev = cur ^ 1;          // tile eintile's buffers
                const int we = (tid >> 6) - 4;     // 0..3
                const int lane = tid & 63;
                const int q2 = lane >> 4;          // 0..3
                const int ln = lane & 15;
                const int g = we * 2 + (q2 >> 1);  // 0..7
                const int so = (q2 & 1) * 16;
                const int ln4 = ln * 4;
                const float4 Lv0 = *(const float4*)&bufL[prev][g][  0 + ln4];
                const float4 Lv1 = *(const float4*)&bufL[prev][g][ 64 + ln4];
                const float4 Lv2 = *(const float4*)&bufL[prev][g][128 + ln4];
                const float4 Lv3 = *(const float4*)&bufL[prev][g][192 + ln4];
                const int* adjq = s_adj[prev][g];
                float kf = 0.0f;                   // lane ln keeps sample so+ln

                float4 fA0, fA1, fA2, fA3, fB0, fB1, fB2, fB3;

#define EIN_LOAD(B0, B1, B2, B3, SIDX) do {                                 \
                const size_t b_ = (size_t)adjq[(SIDX)] * NODE_DIM + ln4;    \
                B0 = load4<ISF32>(features, b_ +   0);                      \
                B1 = load4<ISF32>(features, b_ +  64);                      \
                B2 = load4<ISF32>(features, b_ + 128);                      \
                B3 = load4<ISF32>(features, b_ + 192);                      \
            } while (0)

#define EIN_COMPUTE(B0, B1, B2, B3, SILOC) do {                             \
                double a_ = 0.0;                                            \
                a_ = fma((double)B0.x, (double)Lv0.x, a_);                  \
                a_ = fma((double)B0.y, (double)Lv0.y, a_);                  \
                a_ = fma((double)B0.z, (double)Lv0.z, a_);                  \
                a_ = fma((double)B0.w, (double)Lv0.w, a_);                  \
                a_ = fma((double)B1.x, (double)Lv1.x, a_);                  \
                a_ = fma((double)B1.y, (double)Lv1.y, a_);                  \
                a_ = fma((double)B1.z, (double)Lv1.z, a_);                  \
                a_ = fma((double)B1.w, (double)Lv1.w, a_);                  \
                a_ = fma((double)B2.x, (double)Lv2.x, a_);                  \
                a_ = fma((double)B2.y, (double)Lv2.y, a_);                  \
                a_ = fma((double)B2.z, (double)Lv2.z, a_);                  \
                a_ = fma((double)B2.w, (double)Lv2.w, a_);                  \
                a_ = fma((double)B3.x, (double)Lv3.x, a_);                  \
                a_ = fma((double)B3.y, (double)Lv3.y, a_);                  \
                a_ = fma((double)B3.z, (double)Lv3.z, a_);                  \
                a_ = fma((double)B3.w, (double)Lv3.w, a_);                  \
                a_ += __shfl_xor(a_, 8);                                    \
                a_ += __shfl_xor(a_, 4);                                    \
                a_ += __shfl_xor(a_, 2);                                    \
                a_ += __shfl_xor(a_, 1);                                    \
                kf = ((SILOC) == ln) ? (float)a_ : kf;                      \
            } while (0)

                EIN_LOAD(fA0, fA1, fA2, fA3, so + 0);
                #pragma unroll
                for (int si = 0; si < 16; si += 2) {
                    EIN_LOAD(fB0, fB1, fB2, fB3, so + si + 1);
                    EIN_COMPUTE(fA0, fA1, fA2, fA3, si);
                    if (si + 2 < 16) EIN_LOAD(fA0, fA1, fA2, fA3, so + si + 2);
                    EIN_COMPUTE(fB0, fB1, fB2, fB3, si + 1);
                }
#undef EIN_LOAD
#undef EIN_COMPUTE

                // ---- epilogue (R4 reduction order, register/shuffle form) ----
                const float o = fmaxf(kf, 0.0f);
                const double od = (double)o;
                const double oo = __shfl_xor(od, 16);
                double ssum = od + oo;             // == o[ln] + o[ln+16] (exact commute)
                ssum += __shfl_xor(ssum, 8);
                ssum += __shfl_xor(ssum, 4);
                ssum += __shfl_xor(ssum, 2);
                ssum += __shfl_xor(ssum, 1);
                const float mean = (float)(ssum * (1.0 / 32.0));
                const float thr = 0.5f * mean;
                const int sl = lane & 31;
                const int nb = adjq[sl];
                const bool c = (nb == SENTINEL) || (o > thr);
                const int v = v_blk + eintile * TVPB + g;
                const size_t ob = (size_t)v * NUM_SAMPLES;
                out[ADJ_OFF + ob + sl] = c ? (float)SENTINEL : (float)nb;
                out[ATT_OFF + ob + sl] = 1.0f;
                const unsigned long long bal = __ballot(!c);
                if (sl == 0) {
                    const unsigned long long m =
                        (lane < 32) ? 0xFFFFFFFFull : 0xFFFFFFFF00000000ull;
                    out[NNZ_OFF + v] = (float)__popcll(bal & m);
                    out[MEAN_OFF + v] = mean;
                }
            }
        }
        __syncthreads();
        cur ^= 1;
    }
}

__global__ __launch_bounds__(NTHR, 6)
void FastMLNeighborSampler___9337258901923_kernel(
    const int* ids,
    const int* unif_rand,
    const int* adj_info,
    const void* features_raw,
    const void* W_raw,
    const void* bias_raw,
    float* out) {
    __shared__ float bufA[2][TVPB][NODE_DIM + 4];
    __shared__ float bufL[2][TVPB][NODE_DIM + 4];
    __shared__ int s_adj[2][TVPB][NUM_SAMPLES];
    __shared__ int s_ur[NUM_SAMPLES];
    __shared__ int s_isf32;

    const int tid = threadIdx.x;
    const int v_blk = blockIdx.x * VPBLK;

    if (tid == 0) s_isf32 = probe_isf32(features_raw);
    if (tid < NUM_SAMPLES) s_ur[tid] = unif_rand[tid];
    __syncthreads();

    if (s_isf32) {
        body<1>(ids, adj_info, features_raw, W_raw, bias_raw, out,
                bufA, bufL, s_adj, s_ur, tid, v_blk);
    } else {
        body<0>(ids, adj_info, features_raw, W_raw, bias_raw, out,
                bufA, bufL, s_adj, s_ur, tid, v_blk);
    }
}

extern "C" void kernel_launch(void* const* d_in, const int* in_sizes, int n_in,
                              void* d_out, int out_size, void* d_ws, size_t ws_size,
                              hipStream_t stream) {
    const int* ids = nullptr;
    const int* unif_rand = nullptr;
    const int* adj_info = nullptr;
    const void* features = nullptr;
    const void* W = nullptr;
    const void* bias = nullptr;
    for (int i = 0; i < n_in; ++i) {
        switch (in_sizes[i]) {
            case VERT_NUM:               ids       = (const int*)d_in[i]; break;
            case NUM_SAMPLES:            unif_rand = (const int*)d_in[i]; break;
            case NUM_NODES * MAX_DEGREE: adj_info  = (const int*)d_in[i]; break;
            case NUM_NODES * NODE_DIM:   features  = (const void*)d_in[i]; break;
            case NODE_DIM * NODE_DIM:    W         = (const void*)d_in[i]; break;
            case NODE_DIM:               bias      = (const void*)d_in[i]; break;
            default: break;
        }
    }
    if (!ids || !unif_rand || !adj_info || !features || !W || !bias) {
        ids       = (const int*)d_in[0];
        unif_rand = (const int*)d_in[1];
        adj_info  = (const int*)d_in[2];
        features  = (const void*)d_in[3];
        W         = (const void*)d_in[4];
        bias      = (const void*)d_in[5];
    }
    float* out = (float*)d_out;

    FastMLNeighborSampler___9337258901923_kernel<<<NBLK, NTHR, 0, stream>>>(
        ids, unif_rand, adj_info, features, W, bias, out);
}

// Round 9
// 314.652 us; speedup vs baseline: 1.0867x; 1.0867x over previous
//
#include <hip/hip_runtime.h>

// Problem constants (from reference)
#define NUM_NODES 100000
#define MAX_DEGREE 128
#define NODE_DIM 256
#define VERT_NUM 16384
#define NUM_SAMPLES 32
#define SENTINEL (NUM_NODES - 1)

#define TVPB 8                    // vertices per tile
#define TILES 2                   // tiles per block (both pre-staged in prologue)
#define VPBLK (TVPB * TILES)      // 16 vertices per block
#define NBLK (VERT_NUM / VPBLK)   // 1024 blocks
#define NTHR 512                  // waves 0-3: matmul (mm), waves 4-7: einsum (ein)

// Output layout (FLOAT32 elements), concatenated in reference return order:
// adj_out [V*S] | att_lists [V*S] | adj_lists_numnz [V] | out_mean [V]
#define ADJ_OFF 0
#define ATT_OFF (VERT_NUM * NUM_SAMPLES)
#define NNZ_OFF (2 * VERT_NUM * NUM_SAMPLES)
#define MEAN_OFF (2 * VERT_NUM * NUM_SAMPLES + VERT_NUM)

__device__ __forceinline__ float bfbits2f(unsigned int bits16) {
    return __uint_as_float(bits16 << 16);
}

// Probe: is float storage f32 (1) or packed bf16 (0)?
__device__ __forceinline__ int probe_isf32(const void* p) {
    const unsigned int* fu = (const unsigned int*)p;
    int cnt = 0;
    for (int i = 0; i < 64; ++i) {
        const unsigned int w = fu[i];
        const unsigned int e2 = (w >> 7) & 0xFFu;
        if (e2 >= 90u && e2 <= 140u && (w & 0xFFFFu) != 0u) ++cnt;
    }
    return (cnt >= 40) ? 0 : 1;
}

// Templated loads: no per-element select, vectorized when f32.
template <int ISF32>
__device__ __forceinline__ float ld1(const void* p, size_t idx) {
    if (ISF32) return ((const float*)p)[idx];
    return bfbits2f(((const unsigned short*)p)[idx]);
}

template <int ISF32>
__device__ __forceinline__ float4 load4(const void* p, size_t idx) {
    if (ISF32) {
        return *(const float4*)((const float*)p + idx);
    } else {
        const ushort4 u = *(const ushort4*)((const unsigned short*)p + idx);
        float4 v;
        v.x = bfbits2f(u.x); v.y = bfbits2f(u.y);
        v.z = bfbits2f(u.z); v.w = bfbits2f(u.w);
        return v;
    }
}

// ---------------------------------------------------------------------------
// R9 = R8 (bit-exact wave-specialized pipeline) minus the spill:
//   1. __launch_bounds__(512, 2): RA budget ~256 VGPR so mm path (acc[8]) and
//      ein path (Lv + fA + fB) both fit in registers. R8's (512,6) produced
//      the VGPR=40 + 154 MB scratch-spill signature (WRITE_SIZE counter).
//   2. Both tiles' A rows + adj pre-staged in the prologue (TILES=2 allows
//      it) -> no in-loop staging registers with matmul-long liveness.
// Slots: s0: mm(t0) | s1: mm(t1) || ein(t0) | s2: ein(t1).
// All arithmetic byte-for-byte R8 (absmax 0.0) -> bit-identical outputs.
// ---------------------------------------------------------------------------
template <int ISF32>
__device__ __forceinline__ void body(
    const int* __restrict__ ids,
    const int* __restrict__ adj_info,
    const void* __restrict__ features,
    const void* __restrict__ W,
    const void* __restrict__ bias,
    float* __restrict__ out,
    float (*bufA)[TVPB][NODE_DIM + 4],
    float (*bufL)[TVPB][NODE_DIM + 4],
    int (*s_adj)[TVPB][NUM_SAMPLES],
    const int* s_ur,
    int tid, int v_blk)
{
    // ---- prologue: stage BOTH tiles (A rows + adj), all 512 threads ----
    #pragma unroll
    for (int t = 0; t < TILES; ++t) {
        const int r = tid >> 6;          // 0..7 (wave-uniform)
        const int cg = (tid & 63) * 4;   // 0..252
        const float4 v = load4<ISF32>(features,
            (size_t)ids[v_blk + t * TVPB + r] * NODE_DIM + cg);
        *(float4*)&bufA[t][r][cg] = v;
    }
    {
        const int t  = tid >> 8;         // 0..1
        const int rr = (tid >> 5) & 7;   // 0..7
        const int ss = tid & 31;
        s_adj[t][rr][ss] =
            adj_info[(size_t)ids[v_blk + t * TVPB + rr] * MAX_DEGREE + s_ur[ss]];
    }
    __syncthreads();

    int cur = 0;
    for (int s = 0; s < TILES + 1; ++s) {
        if (tid < 256) {
            // =================== mm role ===================
            const int mmtile = s;
            if (mmtile < TILES) {
                // ---- matmul tile mmtile: bufA[cur] -> bufL[cur] (R4 verbatim) ----
                const int col = tid;
                double acc[TVPB];
                #pragma unroll
                for (int g = 0; g < TVPB; ++g) acc[g] = 0.0;
                float wn0 = ld1<ISF32>(W, (size_t)0 * NODE_DIM + col);
                float wn1 = ld1<ISF32>(W, (size_t)1 * NODE_DIM + col);
                float wn2 = ld1<ISF32>(W, (size_t)2 * NODE_DIM + col);
                float wn3 = ld1<ISF32>(W, (size_t)3 * NODE_DIM + col);
                #pragma unroll 2
                for (int k = 0; k < NODE_DIM; k += 4) {
                    const double w0 = (double)wn0;
                    const double w1 = (double)wn1;
                    const double w2 = (double)wn2;
                    const double w3 = (double)wn3;
                    if (k + 4 < NODE_DIM) {
                        wn0 = ld1<ISF32>(W, (size_t)(k + 4) * NODE_DIM + col);
                        wn1 = ld1<ISF32>(W, (size_t)(k + 5) * NODE_DIM + col);
                        wn2 = ld1<ISF32>(W, (size_t)(k + 6) * NODE_DIM + col);
                        wn3 = ld1<ISF32>(W, (size_t)(k + 7) * NODE_DIM + col);
                    }
                    #pragma unroll
                    for (int g = 0; g < TVPB; ++g) {
                        const float4 a = *(const float4*)&bufA[cur][g][k];
                        acc[g] = fma((double)a.x, w0, acc[g]);
                        acc[g] = fma((double)a.y, w1, acc[g]);
                        acc[g] = fma((double)a.z, w2, acc[g]);
                        acc[g] = fma((double)a.w, w3, acc[g]);
                    }
                }
                const double bv = (double)ld1<ISF32>(bias, (size_t)col);
                #pragma unroll
                for (int g = 0; g < TVPB; ++g)
                    bufL[cur][g][col] = (float)(acc[g] + bv);
            }
        } else {
            // =================== ein role ===================
            const int eintile = s - 1;
            if (eintile >= 0) {
                const int prev = cur ^ 1;          // tile eintile's L buffer
                const int we = (tid >> 6) - 4;     // 0..3
                const int lane = tid & 63;
                const int q2 = lane >> 4;          // 0..3
                const int ln = lane & 15;
                const int g = we * 2 + (q2 >> 1);  // 0..7
                const int so = (q2 & 1) * 16;
                const int ln4 = ln * 4;
                const float4 Lv0 = *(const float4*)&bufL[prev][g][  0 + ln4];
                const float4 Lv1 = *(const float4*)&bufL[prev][g][ 64 + ln4];
                const float4 Lv2 = *(const float4*)&bufL[prev][g][128 + ln4];
                const float4 Lv3 = *(const float4*)&bufL[prev][g][192 + ln4];
                const int* adjq = s_adj[eintile][g];
                float kf = 0.0f;                   // lane ln keeps sample so+ln

                float4 fA0, fA1, fA2, fA3, fB0, fB1, fB2, fB3;

#define EIN_LOAD(B0, B1, B2, B3, SIDX) do {                                 \
                const size_t b_ = (size_t)adjq[(SIDX)] * NODE_DIM + ln4;    \
                B0 = load4<ISF32>(features, b_ +   0);                      \
                B1 = load4<ISF32>(features, b_ +  64);                      \
                B2 = load4<ISF32>(features, b_ + 128);                      \
                B3 = load4<ISF32>(features, b_ + 192);                      \
            } while (0)

#define EIN_COMPUTE(B0, B1, B2, B3, SILOC) do {                             \
                double a_ = 0.0;                                            \
                a_ = fma((double)B0.x, (double)Lv0.x, a_);                  \
                a_ = fma((double)B0.y, (double)Lv0.y, a_);                  \
                a_ = fma((double)B0.z, (double)Lv0.z, a_);                  \
                a_ = fma((double)B0.w, (double)Lv0.w, a_);                  \
                a_ = fma((double)B1.x, (double)Lv1.x, a_);                  \
                a_ = fma((double)B1.y, (double)Lv1.y, a_);                  \
                a_ = fma((double)B1.z, (double)Lv1.z, a_);                  \
                a_ = fma((double)B1.w, (double)Lv1.w, a_);                  \
                a_ = fma((double)B2.x, (double)Lv2.x, a_);                  \
                a_ = fma((double)B2.y, (double)Lv2.y, a_);                  \
                a_ = fma((double)B2.z, (double)Lv2.z, a_);                  \
                a_ = fma((double)B2.w, (double)Lv2.w, a_);                  \
                a_ = fma((double)B3.x, (double)Lv3.x, a_);                  \
                a_ = fma((double)B3.y, (double)Lv3.y, a_);                  \
                a_ = fma((double)B3.z, (double)Lv3.z, a_);                  \
                a_ = fma((double)B3.w, (double)Lv3.w, a_);                  \
                a_ += __shfl_xor(a_, 8);                                    \
                a_ += __shfl_xor(a_, 4);                                    \
                a_ += __shfl_xor(a_, 2);                                    \
                a_ += __shfl_xor(a_, 1);                                    \
                kf = ((SILOC) == ln) ? (float)a_ : kf;                      \
            } while (0)

                EIN_LOAD(fA0, fA1, fA2, fA3, so + 0);
                #pragma unroll
                for (int si = 0; si < 16; si += 2) {
                    EIN_LOAD(fB0, fB1, fB2, fB3, so + si + 1);
                    EIN_COMPUTE(fA0, fA1, fA2, fA3, si);
                    if (si + 2 < 16) EIN_LOAD(fA0, fA1, fA2, fA3, so + si + 2);
                    EIN_COMPUTE(fB0, fB1, fB2, fB3, si + 1);
                }
#undef EIN_LOAD
#undef EIN_COMPUTE

                // ---- epilogue (R4 reduction order, register/shuffle form) ----
                const float o = fmaxf(kf, 0.0f);
                const double od = (double)o;
                const double oo = __shfl_xor(od, 16);
                double ssum = od + oo;             // == o[ln] + o[ln+16] (exact commute)
                ssum += __shfl_xor(ssum, 8);
                ssum += __shfl_xor(ssum, 4);
                ssum += __shfl_xor(ssum, 2);
                ssum += __shfl_xor(ssum, 1);
                const float mean = (float)(ssum * (1.0 / 32.0));
                const float thr = 0.5f * mean;
                const int sl = lane & 31;
                const int nb = adjq[sl];
                const bool c = (nb == SENTINEL) || (o > thr);
                const int v = v_blk + eintile * TVPB + g;
                const size_t ob = (size_t)v * NUM_SAMPLES;
                out[ADJ_OFF + ob + sl] = c ? (float)SENTINEL : (float)nb;
                out[ATT_OFF + ob + sl] = 1.0f;
                const unsigned long long bal = __ballot(!c);
                if (sl == 0) {
                    const unsigned long long m =
                        (lane < 32) ? 0xFFFFFFFFull : 0xFFFFFFFF00000000ull;
                    out[NNZ_OFF + v] = (float)__popcll(bal & m);
                    out[MEAN_OFF + v] = mean;
                }
            }
        }
        __syncthreads();
        cur ^= 1;
    }
}

__global__ __launch_bounds__(NTHR, 2)
void FastMLNeighborSampler___9337258901923_kernel(
    const int* ids,
    const int* unif_rand,
    const int* adj_info,
    const void* features_raw,
    const void* W_raw,
    const void* bias_raw,
    float* out) {
    __shared__ float bufA[2][TVPB][NODE_DIM + 4];
    __shared__ float bufL[2][TVPB][NODE_DIM + 4];
    __shared__ int s_adj[2][TVPB][NUM_SAMPLES];
    __shared__ int s_ur[NUM_SAMPLES];
    __shared__ int s_isf32;

    const int tid = threadIdx.x;
    const int v_blk = blockIdx.x * VPBLK;

    if (tid == 0) s_isf32 = probe_isf32(features_raw);
    if (tid < NUM_SAMPLES) s_ur[tid] = unif_rand[tid];
    __syncthreads();

    if (s_isf32) {
        body<1>(ids, adj_info, features_raw, W_raw, bias_raw, out,
                bufA, bufL, s_adj, s_ur, tid, v_blk);
    } else {
        body<0>(ids, adj_info, features_raw, W_raw, bias_raw, out,
                bufA, bufL, s_adj, s_ur, tid, v_blk);
    }
}

extern "C" void kernel_launch(void* const* d_in, const int* in_sizes, int n_in,
                              void* d_out, int out_size, void* d_ws, size_t ws_size,
                              hipStream_t stream) {
    const int* ids = nullptr;
    const int* unif_rand = nullptr;
    const int* adj_info = nullptr;
    const void* features = nullptr;
    const void* W = nullptr;
    const void* bias = nullptr;
    for (int i = 0; i < n_in; ++i) {
        switch (in_sizes[i]) {
            case VERT_NUM:               ids       = (const int*)d_in[i]; break;
            case NUM_SAMPLES:            unif_rand = (const int*)d_in[i]; break;
            case NUM_NODES * MAX_DEGREE: adj_info  = (const int*)d_in[i]; break;
            case NUM_NODES * NODE_DIM:   features  = (const void*)d_in[i]; break;
            case NODE_DIM * NODE_DIM:    W         = (const void*)d_in[i]; break;
            case NODE_DIM:               bias      = (const void*)d_in[i]; break;
            default: break;
        }
    }
    if (!ids || !unif_rand || !adj_info || !features || !W || !bias) {
        ids       = (const int*)d_in[0];
        unif_rand = (const int*)d_in[1];
        adj_info  = (const int*)d_in[2];
        features  = (const void*)d_in[3];
        W         = (const void*)d_in[4];
        bias      = (const void*)d_in[5];
    }
    float* out = (float*)d_out;

    FastMLNeighborSampler___9337258901923_kernel<<<NBLK, NTHR, 0, stream>>>(
        ids, unif_rand, adj_info, features, W, bias, out);
}

// Round 10
// 289.305 us; speedup vs baseline: 1.1819x; 1.0876x over previous
//
#include <hip/hip_runtime.h>

// Problem constants (from reference)
#define NUM_NODES 100000
#define MAX_DEGREE 128
#define NODE_DIM 256
#define VERT_NUM 16384
#define NUM_SAMPLES 32
#define SENTINEL (NUM_NODES - 1)

#define VPB 8                    // vertices per block
#define NBLK (VERT_NUM / VPB)    // 2048 blocks = 8 blocks/CU on 256 CUs

// Output layout (FLOAT32 elements), concatenated in reference return order:
// adj_out [V*S] | att_lists [V*S] | adj_lists_numnz [V] | out_mean [V]
#define ADJ_OFF 0
#define ATT_OFF (VERT_NUM * NUM_SAMPLES)
#define NNZ_OFF (2 * VERT_NUM * NUM_SAMPLES)
#define MEAN_OFF (2 * VERT_NUM * NUM_SAMPLES + VERT_NUM)

__device__ __forceinline__ float bfbits2f(unsigned int bits16) {
    return __uint_as_float(bits16 << 16);
}

// Probe: is float storage f32 (1) or packed bf16 (0)?
__device__ __forceinline__ int probe_isf32(const void* p) {
    const unsigned int* fu = (const unsigned int*)p;
    int cnt = 0;
    for (int i = 0; i < 64; ++i) {
        const unsigned int w = fu[i];
        const unsigned int e2 = (w >> 7) & 0xFFu;
        if (e2 >= 90u && e2 <= 140u && (w & 0xFFFFu) != 0u) ++cnt;
    }
    return (cnt >= 40) ? 0 : 1;
}

// Templated loads: no per-element select, vectorized when f32.
template <int ISF32>
__device__ __forceinline__ float ld1(const void* p, size_t idx) {
    if (ISF32) return ((const float*)p)[idx];
    return bfbits2f(((const unsigned short*)p)[idx]);
}

template <int ISF32>
__device__ __forceinline__ float4 load4(const void* p, size_t idx) {
    if (ISF32) {
        return *(const float4*)((const float*)p + idx);
    } else {
        const ushort4 u = *(const ushort4*)((const unsigned short*)p + idx);
        float4 v;
        v.x = bfbits2f(u.x); v.y = bfbits2f(u.y);
        v.z = bfbits2f(u.z); v.w = bfbits2f(u.w);
        return v;
    }
}

// ---------------------------------------------------------------------------
// R10 = R4 champion structure (staging / matmul / s_out / epilogue verbatim)
// with the einsum restructured for latency tolerance:
//   * one FULL WAVE per neighbor row: lane takes float4 at lane*4
//     -> 1 VMEM instr/sample (was 4), 4-FMA chain (was 16), 64-lane fp64
//     xor-butterfly (1,2,4,8,16,32) reduction
//   * 8-deep rotating row pipeline (f0..f7, fully static unroll, 32 VGPR)
//     -> 8 rows in flight per wave vs 2 before
// fp64 accumulation of exact f32 products; f32 materialization at l and out.
// The butterfly is an fp64 reorder — same class as the sequential->tree-16
// reorders that have passed absmax 0.0 for six rounds.
// ---------------------------------------------------------------------------
template <int ISF32>
__device__ __forceinline__ void body(
    const int* __restrict__ adj_info,
    const void* __restrict__ features,
    const void* __restrict__ W,
    const void* __restrict__ bias,
    float* __restrict__ out,
    float (*AL_s)[NODE_DIM + 4],
    const int* s_ids,
    const int* s_ur,
    int (*s_adj)[NUM_SAMPLES],
    float (*s_out)[NUM_SAMPLES],
    int tid, int v0)
{
    // ---- stage gathered feature rows into LDS as f32 (coalesced float4) ----
    #pragma unroll
    for (int i = 0; i < 2; ++i) {
        const int idx = tid + i * 256;   // 0..511
        const int r = idx >> 6;          // 0..7 (uniform per wave)
        const int cg = (idx & 63) * 4;   // 0..252
        const float4 v = load4<ISF32>(features, (size_t)s_ids[r] * NODE_DIM + cg);
        *(float4*)&AL_s[r][cg] = v;
    }
    // gather adj samples: one per thread (8*32 = 256)
    {
        const int r = tid >> 5;
        const int s = tid & 31;
        s_adj[r][s] = adj_info[(size_t)s_ids[r] * MAX_DEGREE + s_ur[s]];
    }
    __syncthreads();

    // ---- l = A@W + b; thread = output column, fp64 accumulate (R4 verbatim) ----
    double acc[VPB];
    {
        const int col = tid;
        #pragma unroll
        for (int g = 0; g < VPB; ++g) acc[g] = 0.0;
        float wn0 = ld1<ISF32>(W, (size_t)0 * NODE_DIM + col);
        float wn1 = ld1<ISF32>(W, (size_t)1 * NODE_DIM + col);
        float wn2 = ld1<ISF32>(W, (size_t)2 * NODE_DIM + col);
        float wn3 = ld1<ISF32>(W, (size_t)3 * NODE_DIM + col);
        #pragma unroll 2
        for (int k = 0; k < NODE_DIM; k += 4) {
            const double w0 = (double)wn0;
            const double w1 = (double)wn1;
            const double w2 = (double)wn2;
            const double w3 = (double)wn3;
            if (k + 4 < NODE_DIM) {   // prefetch next quad during FMAs
                wn0 = ld1<ISF32>(W, (size_t)(k + 4) * NODE_DIM + col);
                wn1 = ld1<ISF32>(W, (size_t)(k + 5) * NODE_DIM + col);
                wn2 = ld1<ISF32>(W, (size_t)(k + 6) * NODE_DIM + col);
                wn3 = ld1<ISF32>(W, (size_t)(k + 7) * NODE_DIM + col);
            }
            #pragma unroll
            for (int g = 0; g < VPB; ++g) {
                const float4 a = *(const float4*)&AL_s[g][k];
                acc[g] = fma((double)a.x, w0, acc[g]);
                acc[g] = fma((double)a.y, w1, acc[g]);
                acc[g] = fma((double)a.z, w2, acc[g]);
                acc[g] = fma((double)a.w, w3, acc[g]);
            }
        }
    }
    // all A reads complete before L overwrites the same buffer
    __syncthreads();
    {
        const int col = tid;
        const double bv = (double)ld1<ISF32>(bias, (size_t)col);
        #pragma unroll
        for (int g = 0; g < VPB; ++g) AL_s[g][col] = (float)(acc[g] + bv);
    }
    __syncthreads();

    // ---- einsum: full wave per row, 8-deep pipelined row loads ----
    // Wave wv owns vertices 2wv, 2wv+1 (64 samples sequential).
    {
        const int wv = tid >> 6;         // 0..3
        const int lane = tid & 63;
        const int g0v = wv * 2;
        const int g1v = g0v + 1;
        const int l4 = lane * 4;
        const int* adj0 = s_adj[g0v];
        const int* adj1 = s_adj[g1v];
        float4 Lv = *(const float4*)&AL_s[g0v][l4];
        float4 f0, f1, f2, f3, f4, f5, f6, f7;

#define LOADR(B, ADJ, S) do {                                               \
        B = load4<ISF32>(features, (size_t)(ADJ)[(S)] * NODE_DIM + l4);     \
    } while (0)

#define COMPS(B, G, S) do {                                                 \
        double a_ = 0.0;                                                    \
        a_ = fma((double)B.x, (double)Lv.x, a_);                            \
        a_ = fma((double)B.y, (double)Lv.y, a_);                            \
        a_ = fma((double)B.z, (double)Lv.z, a_);                            \
        a_ = fma((double)B.w, (double)Lv.w, a_);                            \
        a_ += __shfl_xor(a_, 1);                                            \
        a_ += __shfl_xor(a_, 2);                                            \
        a_ += __shfl_xor(a_, 4);                                            \
        a_ += __shfl_xor(a_, 8);                                            \
        a_ += __shfl_xor(a_, 16);                                           \
        a_ += __shfl_xor(a_, 32);                                           \
        if (lane == 0) s_out[(G)][(S)] = (float)a_;                         \
    } while (0)

#define PAIR(B, G, S, ADJ, NS) do { COMPS(B, G, S); LOADR(B, ADJ, NS); } while (0)

#define BLOCK8(G, S0, ADJ, N0)                                              \
        PAIR(f0, G, (S0) + 0, ADJ, (N0) + 0);                               \
        PAIR(f1, G, (S0) + 1, ADJ, (N0) + 1);                               \
        PAIR(f2, G, (S0) + 2, ADJ, (N0) + 2);                               \
        PAIR(f3, G, (S0) + 3, ADJ, (N0) + 3);                               \
        PAIR(f4, G, (S0) + 4, ADJ, (N0) + 4);                               \
        PAIR(f5, G, (S0) + 5, ADJ, (N0) + 5);                               \
        PAIR(f6, G, (S0) + 6, ADJ, (N0) + 6);                               \
        PAIR(f7, G, (S0) + 7, ADJ, (N0) + 7);

#define BLOCK8_END(G, S0)                                                   \
        COMPS(f0, G, (S0) + 0);                                             \
        COMPS(f1, G, (S0) + 1);                                             \
        COMPS(f2, G, (S0) + 2);                                             \
        COMPS(f3, G, (S0) + 3);                                             \
        COMPS(f4, G, (S0) + 4);                                             \
        COMPS(f5, G, (S0) + 5);                                             \
        COMPS(f6, G, (S0) + 6);                                             \
        COMPS(f7, G, (S0) + 7);

        // prologue: fill the 8-deep pipeline with g0's first 8 rows
        LOADR(f0, adj0, 0); LOADR(f1, adj0, 1);
        LOADR(f2, adj0, 2); LOADR(f3, adj0, 3);
        LOADR(f4, adj0, 4); LOADR(f5, adj0, 5);
        LOADR(f6, adj0, 6); LOADR(f7, adj0, 7);

        BLOCK8(g0v,  0, adj0,  8)
        BLOCK8(g0v,  8, adj0, 16)
        BLOCK8(g0v, 16, adj0, 24)
        BLOCK8(g0v, 24, adj1,  0)     // compute g0 tail, prefetch g1 head
        Lv = *(const float4*)&AL_s[g1v][l4];
        BLOCK8(g1v,  0, adj1,  8)
        BLOCK8(g1v,  8, adj1, 16)
        BLOCK8(g1v, 16, adj1, 24)
        BLOCK8_END(g1v, 24)

#undef LOADR
#undef COMPS
#undef PAIR
#undef BLOCK8
#undef BLOCK8_END
    }
    __syncthreads();

    // ---- epilogue: 16 lanes per vertex, 2 samples per lane (R4 verbatim) ----
    if (tid < VPB * 16) {
        const int q = tid >> 4;
        const int ln = tid & 15;
        const int v = v0 + q;
        const float o0 = fmaxf(s_out[q][ln], 0.0f);
        const float o1 = fmaxf(s_out[q][ln + 16], 0.0f);
        double ss = (double)o0 + (double)o1;
        ss += __shfl_xor(ss, 8);
        ss += __shfl_xor(ss, 4);
        ss += __shfl_xor(ss, 2);
        ss += __shfl_xor(ss, 1);
        const float mean = (float)(ss * (1.0 / 32.0));
        const float thr = 0.5f * mean;
        const int n0 = s_adj[q][ln];
        const int n1 = s_adj[q][ln + 16];
        const bool c0 = (n0 == SENTINEL) || (o0 > thr);
        const bool c1 = (n1 == SENTINEL) || (o1 > thr);
        const size_t ob = (size_t)v * NUM_SAMPLES;
        out[ADJ_OFF + ob + ln]      = c0 ? (float)SENTINEL : (float)n0;
        out[ADJ_OFF + ob + ln + 16] = c1 ? (float)SENTINEL : (float)n1;
        out[ATT_OFF + ob + ln]      = 1.0f;
        out[ATT_OFF + ob + ln + 16] = 1.0f;
        int nz = (c0 ? 0 : 1) + (c1 ? 0 : 1);
        nz += __shfl_xor(nz, 8);
        nz += __shfl_xor(nz, 4);
        nz += __shfl_xor(nz, 2);
        nz += __shfl_xor(nz, 1);
        if (ln == 0) {
            out[NNZ_OFF + v] = (float)nz;
            out[MEAN_OFF + v] = mean;
        }
    }
}

__global__ __launch_bounds__(256, 4)
void FastMLNeighborSampler___9337258901923_kernel(
    const int* ids,
    const int* unif_rand,
    const int* adj_info,
    const void* features_raw,
    const void* W_raw,
    const void* bias_raw,
    float* out) {
    __shared__ float AL_s[VPB][NODE_DIM + 4];   // A-tile, then L-tile (overlay)
    __shared__ int s_ids[VPB];
    __shared__ int s_ur[NUM_SAMPLES];
    __shared__ int s_adj[VPB][NUM_SAMPLES];
    __shared__ float s_out[VPB][NUM_SAMPLES];
    __shared__ int s_isf32;

    const int tid = threadIdx.x;
    const int v0 = blockIdx.x * VPB;

    if (tid == 0) s_isf32 = probe_isf32(features_raw);
    if (tid < VPB) {
        s_ids[tid] = ids[v0 + tid];
    } else if (tid < VPB + NUM_SAMPLES) {
        s_ur[tid - VPB] = unif_rand[tid - VPB];
    }
    __syncthreads();

    if (s_isf32) {
        body<1>(adj_info, features_raw, W_raw, bias_raw, out,
                AL_s, s_ids, s_ur, s_adj, s_out, tid, v0);
    } else {
        body<0>(adj_info, features_raw, W_raw, bias_raw, out,
                AL_s, s_ids, s_ur, s_adj, s_out, tid, v0);
    }
}

extern "C" void kernel_launch(void* const* d_in, const int* in_sizes, int n_in,
                              void* d_out, int out_size, void* d_ws, size_t ws_size,
                              hipStream_t stream) {
    const int* ids = nullptr;
    const int* unif_rand = nullptr;
    const int* adj_info = nullptr;
    const void* features = nullptr;
    const void* W = nullptr;
    const void* bias = nullptr;
    for (int i = 0; i < n_in; ++i) {
        switch (in_sizes[i]) {
            case VERT_NUM:               ids       = (const int*)d_in[i]; break;
            case NUM_SAMPLES:            unif_rand = (const int*)d_in[i]; break;
            case NUM_NODES * MAX_DEGREE: adj_info  = (const int*)d_in[i]; break;
            case NUM_NODES * NODE_DIM:   features  = (const void*)d_in[i]; break;
            case NODE_DIM * NODE_DIM:    W         = (const void*)d_in[i]; break;
            case NODE_DIM:               bias      = (const void*)d_in[i]; break;
            default: break;
        }
    }
    if (!ids || !unif_rand || !adj_info || !features || !W || !bias) {
        ids       = (const int*)d_in[0];
        unif_rand = (const int*)d_in[1];
        adj_info  = (const int*)d_in[2];
        features  = (const void*)d_in[3];
        W         = (const void*)d_in[4];
        bias      = (const void*)d_in[5];
    }
    float* out = (float*)d_out;

    FastMLNeighborSampler___9337258901923_kernel<<<NBLK, 256, 0, stream>>>(
        ids, unif_rand, adj_info, features, W, bias, out);
}